// Round 5
// baseline (246.651 us; speedup 1.0000x reference)
//
#include <hip/hip_runtime.h>

// Multi-threshold spiking neuron scan. x: [T*B, C, H, W] fp32, T=4, K=8.
// Per column: mem += x[t]; spike = largest thre[k]=thresh/2^k with
// mem >= 0.75*thre[k]; out[t] = spike; mem -= spike.
//
// R1-R4 all ~85us @ 2.4 TB/s regardless of per-thread MLP -> one-shot wave
// churn suspected. R5: persistent grid-stride waves (1024 blocks = 4/CU,
// always resident), depth-2 pipeline (prefetch next column during compute),
// and exact integer spike math (bits ordering trick) cutting VALU ~6x.

constexpr int T_STEPS = 4;
constexpr int BLOCK = 256;
constexpr int GRID = 1024;   // 4 blocks/CU on 256 CUs: fully resident, no tail

typedef float v4f __attribute__((ext_vector_type(4)));

__device__ __forceinline__ void load4(v4f dst[T_STEPS], const v4f* __restrict__ xv,
                                      size_t n, size_t j) {
#pragma unroll
    for (int t = 0; t < T_STEPS; ++t) dst[t] = xv[(size_t)t * n + j];
}

// Exact spike via fp32 bit ordering (thresh > 0, mem non-NaN):
//   positive fp32 compare == int compare of bit patterns;
//   thr75[k] = 0.75*thresh*2^-k has bits b75_0 - k*2^23 (normal range);
//   smallest crossed k = max(0, ceil((b75_0 - bits(mem)) / 2^23));
//   spike = thresh*2^-k -> bits(thresh) - k*2^23;
//   invalid (mem < thr75[7], incl. mem<=0 via signed compare) -> 0.
__device__ __forceinline__ float spike_of(float mem, int b75_0, int b75_7, int bth0) {
    int u = __float_as_int(mem);
    int d = (int)((unsigned)b75_0 - (unsigned)u);      // wrap-defined
    int k = (int)((unsigned)d + 0x7fffffu) >> 23;      // ceil_div for d>0
    k = k > 0 ? k : 0;                                 // d<=0 -> k=0
    int sb = bth0 - (k << 23);
    return (u >= b75_7) ? __int_as_float(sb) : 0.0f;
}

__device__ __forceinline__ void process(const v4f a[T_STEPS], v4f* __restrict__ ov,
                                        size_t n, size_t j,
                                        int b75_0, int b75_7, int bth0) {
    v4f sp[T_STEPS];
#pragma unroll
    for (int e = 0; e < 4; ++e) {
        float mem = a[0][e];
        float s0 = spike_of(mem, b75_0, b75_7, bth0);
        sp[0][e] = s0;
        mem = mem - s0 + a[1][e];
        float s1 = spike_of(mem, b75_0, b75_7, bth0);
        sp[1][e] = s1;
        mem = mem - s1 + a[2][e];
        float s2 = spike_of(mem, b75_0, b75_7, bth0);
        sp[2][e] = s2;
        mem = mem - s2 + a[3][e];
        sp[3][e] = spike_of(mem, b75_0, b75_7, bth0);
    }
#pragma unroll
    for (int t = 0; t < T_STEPS; ++t)
        __builtin_nontemporal_store(sp[t], &ov[(size_t)t * n + j]);
}

__global__ __launch_bounds__(BLOCK) void snn_mth_kernel(
    const float* __restrict__ x,
    const float* __restrict__ p_thresh,
    float* __restrict__ out,
    int s4)
{
    const float thresh = *p_thresh;
    const int bth0  = __float_as_int(thresh);
    const int b75_0 = __float_as_int(0.75f * thresh);
    const int b75_7 = b75_0 - 7 * 0x800000;

    const v4f* __restrict__ xv = reinterpret_cast<const v4f*>(x);
    v4f* __restrict__ ov = reinterpret_cast<v4f*>(out);

    const size_t n = (size_t)s4;
    const size_t stride = (size_t)GRID * BLOCK;

    size_t jA = (size_t)blockIdx.x * BLOCK + threadIdx.x;
    v4f A[T_STEPS], B[T_STEPS];
    bool actA = jA < n;
    if (actA) load4(A, xv, n, jA);

    while (actA) {
        size_t jB = jA + stride;
        bool actB = jB < n;
        if (actB) load4(B, xv, n, jB);       // prefetch during compute of A
        process(A, ov, n, jA, b75_0, b75_7, bth0);

        size_t jA2 = jB + stride;
        actA = jA2 < n;
        if (actA) load4(A, xv, n, jA2);      // prefetch during compute of B
        if (!actB) break;
        process(B, ov, n, jB, b75_0, b75_7, bth0);
        jA = jA2;
    }
}

extern "C" void kernel_launch(void* const* d_in, const int* in_sizes, int n_in,
                              void* d_out, int out_size, void* d_ws, size_t ws_size,
                              hipStream_t stream) {
    const float* x = (const float*)d_in[0];
    const float* p_thresh = (const float*)d_in[1];
    float* out = (float*)d_out;

    const int total = in_sizes[0];          // T*B*C*H*W
    const int S = total / T_STEPS;          // spatial elements per timestep
    const int s4 = S >> 2;                  // float4 columns

    snn_mth_kernel<<<GRID, BLOCK, 0, stream>>>(x, p_thresh, out, s4);
}

// Round 6
// 234.002 us; speedup vs baseline: 1.0541x; 1.0541x over previous
//
#include <hip/hip_runtime.h>

// Multi-threshold spiking neuron scan. x: [T*B, C, H, W] fp32, T=4, K=8.
// Per column: mem += x[t]; spike = largest thre[k]=thresh/2^k with
// mem >= 0.75*thre[k]; out[t] = spike; mem -= spike.
//
// R1-R5: five structurally different kernels all pinned at ~88us / 2.3 TB/s
// (VALUBusy 8-17%, MLP ample) -> memory-system queuing, not issue or HBM bus.
// R6: XCD-segmented j-sweep. Block b -> segment b%8, so each XCD (round-robin
// dispatch) sweeps its own contiguous 1/8 of the space; the 8 global
// read/write fronts (2^25-byte stride) decorrelate across XCDs instead of
// hitting the same DRAM rows in phase from all 8 L2s.

constexpr int T_STEPS = 4;
constexpr int BLOCK = 256;
constexpr int NXCD = 8;

typedef float v4f __attribute__((ext_vector_type(4)));

// Exact spike via fp32 bit ordering (thresh > 0 normal, mem non-NaN):
// positive fp32 compare == int compare of bits; thr75[k] bits = b75_0 - k*2^23;
// k* = max(0, ceil((b75_0 - bits(mem)) / 2^23)); spike bits = bth0 - k*·2^23;
// mem < thr75[7] (incl. mem<=0, signed cmp) -> 0.  Verified absmax=0 in R5.
__device__ __forceinline__ float spike_of(float mem, int b75_0, int b75_7, int bth0) {
    int u = __float_as_int(mem);
    int d = (int)((unsigned)b75_0 - (unsigned)u);
    int k = (int)((unsigned)d + 0x7fffffu) >> 23;
    k = k > 0 ? k : 0;
    int sb = bth0 - (k << 23);
    return (u >= b75_7) ? __int_as_float(sb) : 0.0f;
}

__global__ __launch_bounds__(BLOCK) void snn_mth_kernel(
    const float* __restrict__ x,
    const float* __restrict__ p_thresh,
    float* __restrict__ out,
    int s4)   // float4 columns per timestep
{
    const float thresh = *p_thresh;
    const int bth0  = __float_as_int(thresh);
    const int b75_0 = __float_as_int(0.75f * thresh);
    const int b75_7 = b75_0 - 7 * 0x800000;

    const v4f* __restrict__ xv = reinterpret_cast<const v4f*>(x);
    v4f* __restrict__ ov = reinterpret_cast<v4f*>(out);

    // XCD-segmented mapping: segment = b % NXCD (matches CP round-robin
    // block->XCD dispatch), slot = b / NXCD sweeps within the segment.
    const int seg_cols   = s4 / (NXCD * BLOCK) * BLOCK;  // cols per segment (whole blocks)
    const int seg_blocks = seg_cols / BLOCK;
    const int main_blocks = seg_blocks * NXCD;

    const int b = blockIdx.x;
    size_t j;
    if (b < main_blocks) {
        const int xcd  = b % NXCD;
        const int slot = b / NXCD;
        j = (size_t)xcd * seg_cols + (size_t)slot * BLOCK + threadIdx.x;
    } else {
        // Tail (empty for the benchmark shape: s4 = 2^21 divides evenly).
        j = (size_t)NXCD * seg_cols + (size_t)(b - main_blocks) * BLOCK + threadIdx.x;
        if (j >= (size_t)s4) return;
    }

    const size_t n = (size_t)s4;

    v4f xc[T_STEPS];
#pragma unroll
    for (int t = 0; t < T_STEPS; ++t)
        xc[t] = xv[(size_t)t * n + j];

    v4f sp[T_STEPS];
#pragma unroll
    for (int e = 0; e < 4; ++e) {
        float mem = xc[0][e];
        float s0 = spike_of(mem, b75_0, b75_7, bth0);
        sp[0][e] = s0;
        mem = mem - s0 + xc[1][e];
        float s1 = spike_of(mem, b75_0, b75_7, bth0);
        sp[1][e] = s1;
        mem = mem - s1 + xc[2][e];
        float s2 = spike_of(mem, b75_0, b75_7, bth0);
        sp[2][e] = s2;
        mem = mem - s2 + xc[3][e];
        sp[3][e] = spike_of(mem, b75_0, b75_7, bth0);
    }

#pragma unroll
    for (int t = 0; t < T_STEPS; ++t)
        __builtin_nontemporal_store(sp[t], &ov[(size_t)t * n + j]);
}

extern "C" void kernel_launch(void* const* d_in, const int* in_sizes, int n_in,
                              void* d_out, int out_size, void* d_ws, size_t ws_size,
                              hipStream_t stream) {
    const float* x = (const float*)d_in[0];
    const float* p_thresh = (const float*)d_in[1];
    float* out = (float*)d_out;

    const int total = in_sizes[0];          // T*B*C*H*W
    const int S = total / T_STEPS;          // spatial elements per timestep
    const int s4 = S >> 2;                  // float4 columns

    const int grid = (s4 + BLOCK - 1) / BLOCK;
    snn_mth_kernel<<<grid, BLOCK, 0, stream>>>(x, p_thresh, out, s4);
}